// Round 8
// baseline (499.687 us; speedup 1.0000x reference)
//
#include <hip/hip_runtime.h>
#include <hip/hip_bf16.h>

// LGA3D2: out = A_g(A_g(x)); A_g is a 5x5 spatial x 3-depth guided aggregation.
// out[b,c,d,h,w] = sum_{i,j in 5x5, k in 0..2} g[b,(i*5+j)*3+k,h,w] * x[b,c,d+k-1,h+i-2,w+j-2]
// x: [B,C,D,H,W] fp32, g: [B,75,H,W] fp32.
//
// R8 = R7 (LDS-staged, double-buffered, reg-staged writes, launch_bounds(256,1))
// with the LDS pipe fixed:
//  - even-pad layout: dword w' stored at w' + 2*(w'>>5)  (2 pads per 32).
//    Every even-w' pair stays contiguous & 8B aligned -> all LDS ops are b64.
//    Banks: pos = 34g+4r+2t (lane=8g+r) -> exactly 4 req/bank/instr = wave64
//    minimum -> conflict-free.
//  - window = 4x ds_read_b64 per row (was 8x b32); stage = 2x ds_write_b64.
//  - all per-lane LDS offsets hoisted to the prologue; row select is a
//    compile-time (a+1)*RPAD immediate -> no addr VALU in the hot loop.

constexpr int RAD = 2;
constexpr int BB = 2, CC = 16, DD = 48, HH = 128, WW = 256;
constexpr int GG = 75;
constexpr int PLANE = HH * WW;

constexpr int WPT = 4;            // outputs per lane along W
constexpr int DPG = 4;            // depths per wave-lane
constexpr int NWV = 4;            // waves per block
constexpr int DCHUNK = 16;        // depths per block
constexpr int NCH = DD / DCHUNK;  // 3
constexpr int SROWS = DCHUNK + 2; // 18 slab rows (d-1 .. d+16)
constexpr int RPAD = 276;         // 260 logical dwords + 2 pads per 32

using uint = unsigned int;

__device__ __forceinline__ constexpr int lpos(int wp) { return wp + 2 * (wp >> 5); }

__device__ __forceinline__ float lo16(uint u) { union {uint i; float f;} c; c.i = u << 16; return c.f; }
__device__ __forceinline__ float hi16(uint u) { union {uint i; float f;} c; c.i = u & 0xFFFF0000u; return c.f; }
__device__ __forceinline__ unsigned short f2bf(float f) {
  union { float f; uint i; } c; c.f = f;
  uint r = c.i + 0x7FFFu + ((c.i >> 16) & 1u);  // round-nearest-even
  return (unsigned short)(r >> 16);
}
__device__ __forceinline__ void store4(float* p, int off, const float* v) {
  float4 t; t.x = v[0]; t.y = v[1]; t.z = v[2]; t.w = v[3];
  *reinterpret_cast<float4*>(p + off) = t;
}
__device__ __forceinline__ void store4(__hip_bfloat16* p, int off, const float* v) {
  ushort4 t; t.x = f2bf(v[0]); t.y = f2bf(v[1]); t.z = f2bf(v[2]); t.w = f2bf(v[3]);
  *reinterpret_cast<ushort4*>(p + off) = t;
}

template <typename IT, typename OT>
__global__ __launch_bounds__(256, 1) void lga_pass(const IT* __restrict__ x,
                                                   const float* __restrict__ g,
                                                   OT* __restrict__ out) {
  __shared__ float lds[2][SROWS][RPAD];   // 39744 B

  // XCD-bijective swizzle; logical order: dch fastest, then h, c, b.
  constexpr int NWG = BB * CC * NCH * HH;   // 12288
  const int bx = blockIdx.x;
  const int lid = (bx & 7) * (NWG >> 3) + (bx >> 3);
  const int dch = lid % NCH;
  const int h   = (lid / NCH) % HH;
  const int c   = (lid / (NCH * HH)) % CC;
  const int b   =  lid / (NCH * HH * CC);

  const int tid = threadIdx.x;
  const int lane = tid & 63;
  const int dg = tid >> 6;                 // wave index (uniform)
  const int w0 = lane * WPT;
  const int d0 = dch * DCHUNK + dg * DPG;

  const IT* xb = x + (size_t)(b * CC + c) * DD * PLANE;
  const float* gb = g + (size_t)b * GG * PLANE;
  const int gbase = h * WW + w0;

  // Hoisted per-lane LDS dword offsets (within a row).
  const int rA = lpos(w0);      // window pairs: w' = w0, w0+2, w0+4, w0+6
  const int rB = lpos(w0 + 2);
  const int rC = lpos(w0 + 4);
  const int rD = lpos(w0 + 6);
  // stage-write pairs: staged w' = w0+2 .. w0+5
  const int sA = rB;            // lpos(w0+2)
  const int sB = rC;            // lpos(w0+4)

  // ---- zero init: w-border dwords (w'=0,1 -> pos 0,1; w'=258,259 -> 274,275)
  if (tid < 2 * SROWS) {
    const int buf = tid / SROWS, s = tid % SROWS;
    lds[buf][s][0] = 0.f; lds[buf][s][1] = 0.f;
    lds[buf][s][274] = 0.f; lds[buf][s][275] = 0.f;
  }
  if (dch == 0)
    for (int idx = tid; idx < 2 * RPAD; idx += 256)
      lds[idx / RPAD][0][idx % RPAD] = 0.f;
  if (dch == NCH - 1)
    for (int idx = tid; idx < 2 * RPAD; idx += 256)
      lds[idx / RPAD][SROWS - 1][idx % RPAD] = 0.f;

  float acc[DPG][WPT];
#pragma unroll
  for (int a = 0; a < DPG; ++a)
#pragma unroll
    for (int q = 0; q < WPT; ++q) acc[a][q] = 0.f;

  const int ilo = (h >= RAD) ? 0 : RAD - h;
  const int him = HH - 1 + RAD - h;
  const int ihi = (him < 4) ? him : 4;

  uint4 sr[5];   // stage regs: wave dg owns slab rows s = dg, dg+4, ...

  auto stage_load = [&](int i) {
    const int hr = h + i - RAD;
#pragma unroll
    for (int t = 0; t < 5; ++t) {
      const int s = dg + NWV * t;
      if (s < SROWS &&
          !(s == 0 && dch == 0) && !(s == SROWS - 1 && dch == NCH - 1)) {
        const int dd = dch * DCHUNK + s - 1;
        if constexpr (sizeof(IT) == 4) {
          sr[t] = *reinterpret_cast<const uint4*>(xb + (size_t)dd * PLANE + hr * WW + w0);
        } else {
          const uint2 u = *reinterpret_cast<const uint2*>(xb + (size_t)dd * PLANE + hr * WW + w0);
          sr[t].x = u.x; sr[t].y = u.y;
        }
      }
    }
  };

  auto stage_write = [&](int buf) {
#pragma unroll
    for (int t = 0; t < 5; ++t) {
      const int s = dg + NWV * t;
      if (s < SROWS &&
          !(s == 0 && dch == 0) && !(s == SROWS - 1 && dch == NCH - 1)) {
        float v0, v1, v2, v3;
        if constexpr (sizeof(IT) == 4) {
          v0 = __uint_as_float(sr[t].x); v1 = __uint_as_float(sr[t].y);
          v2 = __uint_as_float(sr[t].z); v3 = __uint_as_float(sr[t].w);
        } else {
          v0 = lo16(sr[t].x); v1 = hi16(sr[t].x);
          v2 = lo16(sr[t].y); v3 = hi16(sr[t].y);
        }
        float* row = lds[buf][s];
        *reinterpret_cast<float2*>(row + sA) = make_float2(v0, v1);
        *reinterpret_cast<float2*>(row + sB) = make_float2(v2, v3);
      }
    }
  };

  int cur = 0;
  stage_load(ilo);
  stage_write(0);
  __syncthreads();

  for (int ii = ilo; ii <= ihi; ++ii) {
    // Guidance for this i-tap (oldest vmem first; stage loads stay younger).
    float gr[15][WPT];
#pragma unroll
    for (int t = 0; t < 15; ++t) {
      const float4 t4 = *reinterpret_cast<const float4*>(
          gb + (size_t)(ii * 15 + t) * PLANE + gbase);
      gr[t][0] = t4.x; gr[t][1] = t4.y; gr[t][2] = t4.z; gr[t][3] = t4.w;
    }
    if (ii < ihi) stage_load(ii + 1);     // async under compute

    // Per-wave row base for this buffer; row select via compile-time offset.
    const float* base = &lds[cur][dg * DPG][0];
#pragma unroll
    for (int a = -1; a <= DPG; ++a) {     // slab rows d0-1 .. d0+4
      const float* row = base + (a + 1) * RPAD;   // (a+1)*RPAD = ds imm offset
      float2 p0 = *reinterpret_cast<const float2*>(row + rA);
      float2 p1 = *reinterpret_cast<const float2*>(row + rB);
      float2 p2 = *reinterpret_cast<const float2*>(row + rC);
      float2 p3 = *reinterpret_cast<const float2*>(row + rD);
      float v[8] = {p0.x, p0.y, p1.x, p1.y, p2.x, p2.y, p3.x, p3.y};
      // scatter: row d0+a feeds acc[a+1-k] with weight channel j*3+k
#pragma unroll
      for (int k = 0; k < 3; ++k) {
        const int ai = a + 1 - k;
        if (ai < 0 || ai >= DPG) continue;  // compile-time
#pragma unroll
        for (int j = 0; j < 5; ++j)
#pragma unroll
          for (int q = 0; q < WPT; ++q)
            acc[ai][q] = fmaf(gr[j * 3 + k][q], v[q + j], acc[ai][q]);
      }
    }
    if (ii < ihi) stage_write(cur ^ 1);   // vmcnt wait lands after compute
    __syncthreads();
    cur ^= 1;
  }

  OT* ob = out + (size_t)(b * CC + c) * DD * PLANE;
  const int obase = d0 * PLANE + h * WW + w0;
#pragma unroll
  for (int ai = 0; ai < DPG; ++ai) store4(ob, obase + ai * PLANE, acc[ai]);
}

extern "C" void kernel_launch(void* const* d_in, const int* in_sizes, int n_in,
                              void* d_out, int out_size, void* d_ws, size_t ws_size,
                              hipStream_t stream) {
  const float* x = (const float*)d_in[0];
  const float* g = (const float*)d_in[1];
  float* out = (float*)d_out;

  const size_t elems = (size_t)BB * CC * DD * HH * WW;
  const dim3 grid(BB * CC * NCH * HH);   // 12288
  const dim3 block(64 * NWV);            // 256

  if (ws_size >= elems * sizeof(float)) {
    float* y = (float*)d_ws;
    lga_pass<float, float><<<grid, block, 0, stream>>>(x, g, y);
    lga_pass<float, float><<<grid, block, 0, stream>>>(y, g, out);
  } else {
    __hip_bfloat16* y = (__hip_bfloat16*)d_ws;
    lga_pass<float, __hip_bfloat16><<<grid, block, 0, stream>>>(x, g, y);
    lga_pass<__hip_bfloat16, float><<<grid, block, 0, stream>>>(y, g, out);
  }
}

// Round 9
// 443.353 us; speedup vs baseline: 1.1271x; 1.1271x over previous
//
#include <hip/hip_runtime.h>
#include <hip/hip_bf16.h>

// LGA3D2: out = A_g(A_g(x)); A_g is a 5x5 spatial x 3-depth guided aggregation.
// out[b,c,d,h,w] = sum_{i,j in 5x5, k in 0..2} g[b,(i*5+j)*3+k,h,w] * x[b,c,d+k-1,h+i-2,w+j-2]
// x: [B,C,D,H,W] fp32, g: [B,75,H,W] fp32.
//
// R9 = R5 skeleton (async global_load_lds staging, double-buffered across
// i-taps, 4 waves x 64 lanes, block = (b,c,dch=16,h)) with the wounds fixed:
//  - __launch_bounds__(256,1): regalloc free -> no spills (R7/R8 proven).
//  - Row layout sized so each lane's 8-float window is EXACTLY aligned
//    wide reads:  fp32 row [8B pad][1024B core][8B pad] -> 2x ds_read_b128
//    at byte 16*lane (16B lane stride = canonical conflict-free pattern);
//    bf16 row [4B pad][512B core][12B pad] -> 2x ds_read_b64 at 8*lane.
//    Replaces R5's 8-way-conflicted 16B-stride b64 reads (6e7 conflicts).
//  - Core stays linear & contiguous -> global_load_lds-compatible (m104);
//    pads + out-of-range depth rows zeroed once in the prologue.

constexpr int RAD = 2;
constexpr int BB = 2, CC = 16, DD = 48, HH = 128, WW = 256;
constexpr int GG = 75;
constexpr int PLANE = HH * WW;

constexpr int WPT = 4;            // outputs per lane along W
constexpr int DPG = 4;            // depths per wave
constexpr int NWV = 4;            // waves per block
constexpr int DCHUNK = 16;        // depths per block
constexpr int NCH = DD / DCHUNK;  // 3
constexpr int SROWS = DCHUNK + 2; // 18 slab rows (d-1 .. d+16)

using uint = unsigned int;

__device__ __forceinline__ float lo16(uint u) { union {uint i; float f;} c; c.i = u << 16; return c.f; }
__device__ __forceinline__ float hi16(uint u) { union {uint i; float f;} c; c.i = u & 0xFFFF0000u; return c.f; }
__device__ __forceinline__ unsigned short f2bf(float f) {
  union { float f; uint i; } c; c.f = f;
  uint r = c.i + 0x7FFFu + ((c.i >> 16) & 1u);  // round-nearest-even
  return (unsigned short)(r >> 16);
}
__device__ __forceinline__ void store4(float* p, int off, const float* v) {
  float4 t; t.x = v[0]; t.y = v[1]; t.z = v[2]; t.w = v[3];
  *reinterpret_cast<float4*>(p + off) = t;
}
__device__ __forceinline__ void store4(__hip_bfloat16* p, int off, const float* v) {
  ushort4 t; t.x = f2bf(v[0]); t.y = f2bf(v[1]); t.z = f2bf(v[2]); t.w = f2bf(v[3]);
  *reinterpret_cast<ushort4*>(p + off) = t;
}
__device__ __forceinline__ void gload_lds16(const void* gp, void* lp) {
  __builtin_amdgcn_global_load_lds(
      (const __attribute__((address_space(1))) void*)gp,
      (__attribute__((address_space(3))) void*)lp, 16, 0, 0);
}

template <typename IT, typename OT>
__global__ __launch_bounds__(256, 1) void lga_pass(const IT* __restrict__ x,
                                                   const float* __restrict__ g,
                                                   OT* __restrict__ out) {
  constexpr bool F32 = (sizeof(IT) == 4);
  constexpr int COFF = F32 ? 8 : 4;            // core byte offset (low pad)
  constexpr int ROWB = F32 ? 1040 : 528;       // row bytes (16B multiple)
  __shared__ __align__(16) unsigned char lds[2][SROWS * ROWB];  // 37.4K / 19K

  // XCD-bijective swizzle; logical order: dch fastest, then h, c, b.
  constexpr int NWG = BB * CC * NCH * HH;      // 12288
  const int bx = blockIdx.x;
  const int lid = (bx & 7) * (NWG >> 3) + (bx >> 3);
  const int dch = lid % NCH;
  const int h   = (lid / NCH) % HH;
  const int c   = (lid / (NCH * HH)) % CC;
  const int b   =  lid / (NCH * HH * CC);

  const int tid = threadIdx.x;
  const int lane = tid & 63;
  const int dg = tid >> 6;                     // wave index (uniform)
  const int w0 = lane * WPT;
  const int d0 = dch * DCHUNK + dg * DPG;

  const IT* xb = x + (size_t)(b * CC + c) * DD * PLANE;
  const float* gb = g + (size_t)b * GG * PLANE;
  const int gbase = h * WW + w0;

  // ---- zero init: per-row pads (both bufs); full rows for out-of-range depths
  if (tid < 2 * SROWS) {
    const int buf = tid / SROWS, s = tid % SROWS;
    unsigned char* r = &lds[buf][s * ROWB];
    if constexpr (F32) {
      *reinterpret_cast<uint2*>(r) = make_uint2(0, 0);             // 0..7
      *reinterpret_cast<uint2*>(r + ROWB - 8) = make_uint2(0, 0);  // 1032..1039
    } else {
      *reinterpret_cast<uint*>(r) = 0;                             // 0..3
      *reinterpret_cast<uint*>(r + ROWB - 12) = 0;                 // 516..519
      *reinterpret_cast<uint2*>(r + ROWB - 8) = make_uint2(0, 0);  // 520..527
    }
  }
  constexpr int RDW = ROWB / 4;
  if (dch == 0)
    for (int idx = tid; idx < 2 * RDW; idx += 256)
      reinterpret_cast<uint*>(&lds[idx / RDW][0])[idx % RDW] = 0;
  if (dch == NCH - 1)
    for (int idx = tid; idx < 2 * RDW; idx += 256)
      reinterpret_cast<uint*>(&lds[idx / RDW][(SROWS - 1) * ROWB])[idx % RDW] = 0;

  float acc[DPG][WPT];
#pragma unroll
  for (int a = 0; a < DPG; ++a)
#pragma unroll
    for (int q = 0; q < WPT; ++q) acc[a][q] = 0.f;

  const int ilo = (h >= RAD) ? 0 : RAD - h;
  const int him = HH - 1 + RAD - h;
  const int ihi = (him < 4) ? him : 4;

  // Async-stage one i-slab: wave dg stages rows s = dg, dg+4, ...
  auto stage = [&](int buf, int i) {
    const int hr = h + i - RAD;
#pragma unroll
    for (int t = 0; t < 5; ++t) {
      const int s = dg + NWV * t;
      if (s < SROWS &&
          !(s == 0 && dch == 0) && !(s == SROWS - 1 && dch == NCH - 1)) {
        const int dd = dch * DCHUNK + s - 1;
        const IT* gp = xb + (size_t)dd * PLANE + hr * WW;
        void* lp = &lds[buf][s * ROWB + COFF];   // wave-uniform dest base
        if constexpr (F32) {
          gload_lds16(gp + lane * 4, lp);        // 64 lanes x 16B = 1KB
        } else {
          if (lane < 32) gload_lds16(gp + lane * 8, lp);  // 32 x 16B = 512B
        }
      }
    }
  };

  int cur = 0;
  stage(0, ilo);
  __syncthreads();

  // Per-lane window byte base within a row (start = w0-2):
  //   fp32: COFF + 4*(w0-2) = 16*lane ; bf16: COFF + 2*(w0-2) = 8*lane
  const int wbyte = F32 ? (16 * lane) : (8 * lane);

  for (int ii = ilo; ii <= ihi; ++ii) {
    // Guidance for this i-tap (global; L2-resident, shared across c).
    float gr[15][WPT];
#pragma unroll
    for (int t = 0; t < 15; ++t) {
      const float4 t4 = *reinterpret_cast<const float4*>(
          gb + (size_t)(ii * 15 + t) * PLANE + gbase);
      gr[t][0] = t4.x; gr[t][1] = t4.y; gr[t][2] = t4.z; gr[t][3] = t4.w;
    }
    if (ii < ihi) stage(cur ^ 1, ii + 1);       // async, lands under compute

    const unsigned char* wb = &lds[cur][dg * DPG * ROWB] + wbyte;
#pragma unroll
    for (int a = -1; a <= DPG; ++a) {           // slab rows d0-1 .. d0+4
      const unsigned char* rp = wb + (a + 1) * ROWB;  // compile-time ds offset
      float v[8];                               // x at w = w0-2 .. w0+5
      if constexpr (F32) {
        const float4 q0 = *reinterpret_cast<const float4*>(rp);
        const float4 q1 = *reinterpret_cast<const float4*>(rp + 16);
        v[0] = q0.x; v[1] = q0.y; v[2] = q0.z; v[3] = q0.w;
        v[4] = q1.x; v[5] = q1.y; v[6] = q1.z; v[7] = q1.w;
      } else {
        const uint2 q0 = *reinterpret_cast<const uint2*>(rp);
        const uint2 q1 = *reinterpret_cast<const uint2*>(rp + 8);
        v[0] = lo16(q0.x); v[1] = hi16(q0.x); v[2] = lo16(q0.y); v[3] = hi16(q0.y);
        v[4] = lo16(q1.x); v[5] = hi16(q1.x); v[6] = lo16(q1.y); v[7] = hi16(q1.y);
      }
      // scatter: x depth d0+a feeds acc[a+1-k] with weight channel j*3+k
#pragma unroll
      for (int k = 0; k < 3; ++k) {
        const int ai = a + 1 - k;
        if (ai < 0 || ai >= DPG) continue;      // compile-time
#pragma unroll
        for (int j = 0; j < 5; ++j)
#pragma unroll
          for (int q = 0; q < WPT; ++q)
            acc[ai][q] = fmaf(gr[j * 3 + k][q], v[q + j], acc[ai][q]);
      }
    }
    __syncthreads();   // drains stage(ii+1); buf[cur] reads done before reuse
    cur ^= 1;
  }

  OT* ob = out + (size_t)(b * CC + c) * DD * PLANE;
  const int obase = d0 * PLANE + h * WW + w0;
#pragma unroll
  for (int ai = 0; ai < DPG; ++ai) store4(ob, obase + ai * PLANE, acc[ai]);
}

extern "C" void kernel_launch(void* const* d_in, const int* in_sizes, int n_in,
                              void* d_out, int out_size, void* d_ws, size_t ws_size,
                              hipStream_t stream) {
  const float* x = (const float*)d_in[0];
  const float* g = (const float*)d_in[1];
  float* out = (float*)d_out;

  const size_t elems = (size_t)BB * CC * DD * HH * WW;
  const dim3 grid(BB * CC * NCH * HH);   // 12288
  const dim3 block(64 * NWV);            // 256

  if (ws_size >= elems * sizeof(float)) {
    float* y = (float*)d_ws;
    lga_pass<float, float><<<grid, block, 0, stream>>>(x, g, y);
    lga_pass<float, float><<<grid, block, 0, stream>>>(y, g, out);
  } else {
    __hip_bfloat16* y = (__hip_bfloat16*)d_ws;
    lga_pass<float, __hip_bfloat16><<<grid, block, 0, stream>>>(x, g, y);
    lga_pass<__hip_bfloat16, float><<<grid, block, 0, stream>>>(y, g, out);
  }
}

// Round 10
// 443.191 us; speedup vs baseline: 1.1275x; 1.0004x over previous
//
#include <hip/hip_runtime.h>
#include <hip/hip_bf16.h>

// LGA3D2: out = A_g(A_g(x)); A_g is a 5x5 spatial x 3-depth guided aggregation.
// out[b,c,d,h,w] = sum_{i,j in 5x5, k in 0..2} g[b,(i*5+j)*3+k,h,w] * x[b,c,d+k-1,h+i-2,w+j-2]
// x: [B,C,D,H,W] fp32, g: [B,75,H,W] fp32.
//
// R10 = R9 (async global_load_lds staging, dbuf across i-taps, 4 waves,
// block=(b,c,dch=16,h), b128-aligned window layout) + ONE change:
//   amdgpu_waves_per_eu(4,4). Occupancy is LDS-capped at 4 blocks/CU x 4
//   waves = 4 waves/SIMD, which VGPR=128 exactly matches. R9's allocator
//   chose 64 VGPR against ~94 live (gr re-loaded from L1 per use, no ds_read
//   hoisting -> exposed LDS latency). Declaring 4-waves-max removes any
//   incentive to shrink below 128 -> gr stays resident, reads get hoisted.

constexpr int RAD = 2;
constexpr int BB = 2, CC = 16, DD = 48, HH = 128, WW = 256;
constexpr int GG = 75;
constexpr int PLANE = HH * WW;

constexpr int WPT = 4;            // outputs per lane along W
constexpr int DPG = 4;            // depths per wave
constexpr int NWV = 4;            // waves per block
constexpr int DCHUNK = 16;        // depths per block
constexpr int NCH = DD / DCHUNK;  // 3
constexpr int SROWS = DCHUNK + 2; // 18 slab rows (d-1 .. d+16)

using uint = unsigned int;

__device__ __forceinline__ float lo16(uint u) { union {uint i; float f;} c; c.i = u << 16; return c.f; }
__device__ __forceinline__ float hi16(uint u) { union {uint i; float f;} c; c.i = u & 0xFFFF0000u; return c.f; }
__device__ __forceinline__ unsigned short f2bf(float f) {
  union { float f; uint i; } c; c.f = f;
  uint r = c.i + 0x7FFFu + ((c.i >> 16) & 1u);  // round-nearest-even
  return (unsigned short)(r >> 16);
}
__device__ __forceinline__ void store4(float* p, int off, const float* v) {
  float4 t; t.x = v[0]; t.y = v[1]; t.z = v[2]; t.w = v[3];
  *reinterpret_cast<float4*>(p + off) = t;
}
__device__ __forceinline__ void store4(__hip_bfloat16* p, int off, const float* v) {
  ushort4 t; t.x = f2bf(v[0]); t.y = f2bf(v[1]); t.z = f2bf(v[2]); t.w = f2bf(v[3]);
  *reinterpret_cast<ushort4*>(p + off) = t;
}
__device__ __forceinline__ void gload_lds16(const void* gp, void* lp) {
  __builtin_amdgcn_global_load_lds(
      (const __attribute__((address_space(1))) void*)gp,
      (__attribute__((address_space(3))) void*)lp, 16, 0, 0);
}

template <typename IT, typename OT>
__global__ __launch_bounds__(256)
__attribute__((amdgpu_waves_per_eu(4, 4)))
void lga_pass(const IT* __restrict__ x,
              const float* __restrict__ g,
              OT* __restrict__ out) {
  constexpr bool F32 = (sizeof(IT) == 4);
  constexpr int COFF = F32 ? 8 : 4;            // core byte offset (low pad)
  constexpr int ROWB = F32 ? 1040 : 528;       // row bytes (16B multiple)
  __shared__ __align__(16) unsigned char lds[2][SROWS * ROWB];  // 37.4K / 19K

  // XCD-bijective swizzle; logical order: dch fastest, then h, c, b.
  constexpr int NWG = BB * CC * NCH * HH;      // 12288
  const int bx = blockIdx.x;
  const int lid = (bx & 7) * (NWG >> 3) + (bx >> 3);
  const int dch = lid % NCH;
  const int h   = (lid / NCH) % HH;
  const int c   = (lid / (NCH * HH)) % CC;
  const int b   =  lid / (NCH * HH * CC);

  const int tid = threadIdx.x;
  const int lane = tid & 63;
  const int dg = tid >> 6;                     // wave index (uniform)
  const int w0 = lane * WPT;
  const int d0 = dch * DCHUNK + dg * DPG;

  const IT* xb = x + (size_t)(b * CC + c) * DD * PLANE;
  const float* gb = g + (size_t)b * GG * PLANE;
  const int gbase = h * WW + w0;

  // ---- zero init: per-row pads (both bufs); full rows for out-of-range depths
  if (tid < 2 * SROWS) {
    const int buf = tid / SROWS, s = tid % SROWS;
    unsigned char* r = &lds[buf][s * ROWB];
    if constexpr (F32) {
      *reinterpret_cast<uint2*>(r) = make_uint2(0, 0);             // 0..7
      *reinterpret_cast<uint2*>(r + ROWB - 8) = make_uint2(0, 0);  // 1032..1039
    } else {
      *reinterpret_cast<uint*>(r) = 0;                             // 0..3
      *reinterpret_cast<uint*>(r + ROWB - 12) = 0;                 // 516..519
      *reinterpret_cast<uint2*>(r + ROWB - 8) = make_uint2(0, 0);  // 520..527
    }
  }
  constexpr int RDW = ROWB / 4;
  if (dch == 0)
    for (int idx = tid; idx < 2 * RDW; idx += 256)
      reinterpret_cast<uint*>(&lds[idx / RDW][0])[idx % RDW] = 0;
  if (dch == NCH - 1)
    for (int idx = tid; idx < 2 * RDW; idx += 256)
      reinterpret_cast<uint*>(&lds[idx / RDW][(SROWS - 1) * ROWB])[idx % RDW] = 0;

  float acc[DPG][WPT];
#pragma unroll
  for (int a = 0; a < DPG; ++a)
#pragma unroll
    for (int q = 0; q < WPT; ++q) acc[a][q] = 0.f;

  const int ilo = (h >= RAD) ? 0 : RAD - h;
  const int him = HH - 1 + RAD - h;
  const int ihi = (him < 4) ? him : 4;

  // Async-stage one i-slab: wave dg stages rows s = dg, dg+4, ...
  auto stage = [&](int buf, int i) {
    const int hr = h + i - RAD;
#pragma unroll
    for (int t = 0; t < 5; ++t) {
      const int s = dg + NWV * t;
      if (s < SROWS &&
          !(s == 0 && dch == 0) && !(s == SROWS - 1 && dch == NCH - 1)) {
        const int dd = dch * DCHUNK + s - 1;
        const IT* gp = xb + (size_t)dd * PLANE + hr * WW;
        void* lp = &lds[buf][s * ROWB + COFF];   // wave-uniform dest base
        if constexpr (F32) {
          gload_lds16(gp + lane * 4, lp);        // 64 lanes x 16B = 1KB
        } else {
          if (lane < 32) gload_lds16(gp + lane * 8, lp);  // 32 x 16B = 512B
        }
      }
    }
  };

  int cur = 0;
  stage(0, ilo);
  __syncthreads();

  // Per-lane window byte base within a row (start = w0-2):
  //   fp32: COFF + 4*(w0-2) = 16*lane ; bf16: COFF + 2*(w0-2) = 8*lane
  const int wbyte = F32 ? (16 * lane) : (8 * lane);

  for (int ii = ilo; ii <= ihi; ++ii) {
    // Guidance for this i-tap (global; L2-resident, shared across c).
    float gr[15][WPT];
#pragma unroll
    for (int t = 0; t < 15; ++t) {
      const float4 t4 = *reinterpret_cast<const float4*>(
          gb + (size_t)(ii * 15 + t) * PLANE + gbase);
      gr[t][0] = t4.x; gr[t][1] = t4.y; gr[t][2] = t4.z; gr[t][3] = t4.w;
    }
    if (ii < ihi) stage(cur ^ 1, ii + 1);       // async, lands under compute

    const unsigned char* wb = &lds[cur][dg * DPG * ROWB] + wbyte;
#pragma unroll
    for (int a = -1; a <= DPG; ++a) {           // slab rows d0-1 .. d0+4
      const unsigned char* rp = wb + (a + 1) * ROWB;  // compile-time ds offset
      float v[8];                               // x at w = w0-2 .. w0+5
      if constexpr (F32) {
        const float4 q0 = *reinterpret_cast<const float4*>(rp);
        const float4 q1 = *reinterpret_cast<const float4*>(rp + 16);
        v[0] = q0.x; v[1] = q0.y; v[2] = q0.z; v[3] = q0.w;
        v[4] = q1.x; v[5] = q1.y; v[6] = q1.z; v[7] = q1.w;
      } else {
        const uint2 q0 = *reinterpret_cast<const uint2*>(rp);
        const uint2 q1 = *reinterpret_cast<const uint2*>(rp + 8);
        v[0] = lo16(q0.x); v[1] = hi16(q0.x); v[2] = lo16(q0.y); v[3] = hi16(q0.y);
        v[4] = lo16(q1.x); v[5] = hi16(q1.x); v[6] = lo16(q1.y); v[7] = hi16(q1.y);
      }
      // scatter: x depth d0+a feeds acc[a+1-k] with weight channel j*3+k
#pragma unroll
      for (int k = 0; k < 3; ++k) {
        const int ai = a + 1 - k;
        if (ai < 0 || ai >= DPG) continue;      // compile-time
#pragma unroll
        for (int j = 0; j < 5; ++j)
#pragma unroll
          for (int q = 0; q < WPT; ++q)
            acc[ai][q] = fmaf(gr[j * 3 + k][q], v[q + j], acc[ai][q]);
      }
    }
    __syncthreads();   // drains stage(ii+1); buf[cur] reads done before reuse
    cur ^= 1;
  }

  OT* ob = out + (size_t)(b * CC + c) * DD * PLANE;
  const int obase = d0 * PLANE + h * WW + w0;
#pragma unroll
  for (int ai = 0; ai < DPG; ++ai) store4(ob, obase + ai * PLANE, acc[ai]);
}

extern "C" void kernel_launch(void* const* d_in, const int* in_sizes, int n_in,
                              void* d_out, int out_size, void* d_ws, size_t ws_size,
                              hipStream_t stream) {
  const float* x = (const float*)d_in[0];
  const float* g = (const float*)d_in[1];
  float* out = (float*)d_out;

  const size_t elems = (size_t)BB * CC * DD * HH * WW;
  const dim3 grid(BB * CC * NCH * HH);   // 12288
  const dim3 block(64 * NWV);            // 256

  if (ws_size >= elems * sizeof(float)) {
    float* y = (float*)d_ws;
    lga_pass<float, float><<<grid, block, 0, stream>>>(x, g, y);
    lga_pass<float, float><<<grid, block, 0, stream>>>(y, g, out);
  } else {
    __hip_bfloat16* y = (__hip_bfloat16*)d_ws;
    lga_pass<float, __hip_bfloat16><<<grid, block, 0, stream>>>(x, g, y);
    lga_pass<__hip_bfloat16, float><<<grid, block, 0, stream>>>(y, g, out);
  }
}